// Round 6
// baseline (386.555 us; speedup 1.0000x reference)
//
#include <hip/hip_runtime.h>

// ---------------- static problem config ----------------
#define LQN   13294
#define NBAT  2
#define MROWS (NBAT * LQN)   // 26588
#define CCH   256
#define NHEAD 8
#define DHEAD 32
#define NLVL  4
#define NPT   4
#define DFF   2048

typedef short short8 __attribute__((ext_vector_type(8)));
typedef float f32x4 __attribute__((ext_vector_type(4)));
typedef unsigned short u16;
typedef u16 u16x4 __attribute__((ext_vector_type(4)));

__device__ __forceinline__ u16 f2bf(float f) {
  unsigned int u = __builtin_bit_cast(unsigned int, f);
  u += 0x7fffu + ((u >> 16) & 1u);   // RNE
  return (u16)(u >> 16);
}
__device__ __forceinline__ float bf2f(u16 s) {
  unsigned int u = ((unsigned int)s) << 16;
  return __builtin_bit_cast(float, u);
}
__device__ __forceinline__ void async16(const void* g, void* l) {
  __builtin_amdgcn_global_load_lds(
      (const __attribute__((address_space(1))) void*)g,
      (__attribute__((address_space(3))) void*)l, 16, 0, 0);
}

// ---------------- K=256 GEMM: whole-K staged, one barrier ----------------
// C[M,N] = A[M,256] * BT[N,256]^T + bias. BM=BN=128. 128KB dynamic LDS, 4 waves.
// OUT_MODE: 0 = f32 out, 1 = bf16 out
template<int OUT_MODE>
__global__ __launch_bounds__(256, 1)
void gemm_k256(const u16* __restrict__ A, const u16* __restrict__ BT,
               const float* __restrict__ bias, void* __restrict__ Cout,
               int M, int N)
{
  extern __shared__ char smem[];
  char* As = smem;             // [128][512B], chunk-XOR swizzled
  char* Bs = smem + 65536;     // [128][512B]

  const int t    = threadIdx.x;
  const int lane = t & 63;
  const int wid  = t >> 6;
  const int wm   = wid >> 1, wn = wid & 1;
  const int bm   = blockIdx.x, bn = blockIdx.y;
  const int l15  = lane & 15;
  const int kq   = lane >> 4;

  // stage everything: 16 chunks of A + 16 of B per thread, then ONE barrier
#pragma unroll
  for (int i = 0; i < 16; ++i) {
    const int c   = i * 256 + t;
    const int row = c >> 5;                       // 0..127
    const int kgE = ((c & 31) ^ (row & 7)) * 8;   // swizzled k-elem offset
    int ar = bm * 128 + row; ar = ar < M ? ar : M - 1;
    async16(&A[(size_t)ar * 256 + kgE], As + c * 16);
    const int br = bn * 128 + row;                // N multiple of 128
    async16(&BT[(size_t)br * 256 + kgE], Bs + c * 16);
  }

  f32x4 acc[4][4];
#pragma unroll
  for (int m = 0; m < 4; ++m)
#pragma unroll
    for (int n = 0; n < 4; ++n) acc[m][n] = (f32x4)0.0f;

  __syncthreads();

#pragma unroll
  for (int ks = 0; ks < 8; ++ks) {
    short8 af[4], bfr[4];
#pragma unroll
    for (int m = 0; m < 4; ++m) {
      const int row = wm * 64 + m * 16 + l15;
      af[m] = *(const short8*)(As + row * 512 + (((ks * 4 + kq) ^ (row & 7)) << 4));
    }
#pragma unroll
    for (int n = 0; n < 4; ++n) {
      const int col = wn * 64 + n * 16 + l15;
      bfr[n] = *(const short8*)(Bs + col * 512 + (((ks * 4 + kq) ^ (col & 7)) << 4));
    }
#pragma unroll
    for (int m = 0; m < 4; ++m)
#pragma unroll
      for (int n = 0; n < 4; ++n)
        acc[m][n] = __builtin_amdgcn_mfma_f32_16x16x32_bf16(af[m], bfr[n], acc[m][n], 0, 0, 0);
  }

  const int crow0 = bm * 128 + wm * 64;
  const int ccol0 = bn * 128 + wn * 64;
#pragma unroll
  for (int n = 0; n < 4; ++n) {
    int col = ccol0 + n * 16 + l15;
    float bv = bias[col];
#pragma unroll
    for (int m = 0; m < 4; ++m) {
      int rbase = crow0 + m * 16 + kq * 4;
#pragma unroll
      for (int j = 0; j < 4; ++j) {
        int row = rbase + j;
        if (row < M) {
          float v = acc[m][n][j] + bv;
          if constexpr (OUT_MODE == 0) ((float*)Cout)[(size_t)row * N + col] = v;
          else                         ((u16*)Cout)[(size_t)row * N + col] = f2bf(v);
        }
      }
    }
  }
}

// ---------------- fused FFN v3: 1 barrier/chunk staggered pipeline ----------------
// 512 threads (8 waves). Block = 128 rows. DFF chunked by 64 (32 chunks).
// x in regs; W2 B-frags global->regs (dbuf, no LDS); W1 LDS dbuf; ps stride 168B
// (conflict-free without XOR). Body(i): load W2(i)->regs, stage W1(i+1), P(i),
// PV(i-1), ONE barrier.
__global__ __launch_bounds__(512, 2)
void ffn_fused(const u16* __restrict__ x_bf, const u16* __restrict__ W1T,
               const u16* __restrict__ W2T, const float* __restrict__ b1,
               const float* __restrict__ b2, float* __restrict__ out)
{
  extern __shared__ char smem[];
  u16*  w1s0 = (u16*)(smem);            // [64][256] 32KB
  u16*  w1s1 = (u16*)(smem + 32768);
  char* ps0  = smem + 65536;            // [128][168B] = 21504B
  char* ps1  = smem + 65536 + 21504;    // total 108544

  const int t    = threadIdx.x;
  const int lane = t & 63;
  const int wid  = t >> 6;
  const int l15  = lane & 15;
  const int kq   = lane >> 4;
  const int bm   = blockIdx.x;
  const int pwm  = wid >> 1, pwn = wid & 1;   // P-phase: 4x2, tile 32x32
  const int wm   = wid >> 2, wn = wid & 3;    // PV-phase: 2x4, tile 64x64

  // ---- x fragments -> registers (once) ----
  short8 xr[2][8];
#pragma unroll
  for (int m = 0; m < 2; ++m) {
    int ar = bm * 128 + pwm * 32 + m * 16 + l15;
    ar = ar < MROWS ? ar : MROWS - 1;
    const char* xb = (const char*)x_bf + (size_t)ar * 512 + kq * 16;
#pragma unroll
    for (int ks = 0; ks < 8; ++ks)
      xr[m][ks] = *(const short8*)(xb + ks * 64);
  }

  auto stage_w1 = [&](u16* buf, int it) {
#pragma unroll
    for (int i = 0; i < 4; ++i) {
      const int c  = i * 512 + t;
      const int r1 = c >> 5;
      const int k1 = ((c & 31) ^ (r1 & 7)) * 8;
      async16(&W1T[(size_t)(it * 64 + r1) * 256 + k1], &buf[c * 8]);
    }
  };

  f32x4 acc[4][4];
#pragma unroll
  for (int m = 0; m < 4; ++m)
#pragma unroll
    for (int n = 0; n < 4; ++n) acc[m][n] = (f32x4)0.0f;

  short8 w2rA[2][4], w2rB[2][4];   // W2 B-frag double buffer (regs)

  // body(i): doP => compute P(i) [+load W2(i), stage W1(i+1)]; doPV => PV(i-1)
  auto body = [&](int i, bool doPV, bool doP,
                  short8 (&w2u)[2][4], short8 (&w2l)[2][4],
                  const u16* w1u, u16* w1stg, char* psR, char* psW) {
    if (doP) {
      // issue W2 chunk(i) global->regs (consumed next body)
#pragma unroll
      for (int kk = 0; kk < 2; ++kk)
#pragma unroll
        for (int n = 0; n < 4; ++n) {
          const int brow = wn * 64 + n * 16 + l15;
          w2l[kk][n] = *(const short8*)&W2T[(size_t)brow * 2048 + i * 64 + kk * 32 + kq * 8];
        }
      if (i < 31) stage_w1(w1stg, i + 1);

      // ---- P(i) = x @ W1c^T (32x32 per wave) ----
      f32x4 p[2][2];
#pragma unroll
      for (int m = 0; m < 2; ++m)
#pragma unroll
        for (int n = 0; n < 2; ++n) p[m][n] = (f32x4)0.0f;
#pragma unroll
      for (int ks = 0; ks < 8; ++ks) {
        short8 bfr[2];
#pragma unroll
        for (int n = 0; n < 2; ++n) {
          const int wrow = pwn * 32 + n * 16 + l15;
          const int xb   = (ks * 64 + kq * 16) ^ ((wrow & 7) << 4);
          bfr[n] = *(const short8*)((const char*)w1u + wrow * 512 + xb);
        }
#pragma unroll
        for (int m = 0; m < 2; ++m)
#pragma unroll
          for (int n = 0; n < 2; ++n)
            p[m][n] = __builtin_amdgcn_mfma_f32_16x16x32_bf16(xr[m][ks], bfr[n], p[m][n], 0, 0, 0);
      }
      // bias + relu + bf16 -> psW (stride 168B: conflict-free)
#pragma unroll
      for (int n = 0; n < 2; ++n) {
        const int col = pwn * 32 + n * 16 + l15;
        const float bv = b1[i * 64 + col];
#pragma unroll
        for (int m = 0; m < 2; ++m)
#pragma unroll
          for (int j = 0; j < 4; ++j) {
            const int prow = pwm * 32 + m * 16 + kq * 4 + j;
            *(u16*)(psW + prow * 168 + col * 2) = f2bf(fmaxf(p[m][n][j] + bv, 0.0f));
          }
      }
    }

    if (doPV) {
      // ---- acc += P(i-1) @ W2c(i-1) (64x64 per wave) ----
#pragma unroll
      for (int kk = 0; kk < 2; ++kk) {
        short8 paf[4];
#pragma unroll
        for (int m = 0; m < 4; ++m) {
          const int arow = wm * 64 + m * 16 + l15;
          paf[m] = *(const short8*)(psR + arow * 168 + (kk * 4 + kq) * 16);
        }
#pragma unroll
        for (int m = 0; m < 4; ++m)
#pragma unroll
          for (int n = 0; n < 4; ++n)
            acc[m][n] = __builtin_amdgcn_mfma_f32_16x16x32_bf16(paf[m], w2u[kk][n], acc[m][n], 0, 0, 0);
      }
    }

    if (doP) __syncthreads();
  };

  stage_w1(w1s0, 0);
  __syncthreads();

  body(0, false, true, w2rB, w2rA, w1s0, w1s1, ps1, ps0);
  for (int tt = 0; tt < 15; ++tt) {
    body(2 * tt + 1, true, true, w2rA, w2rB, w1s1, w1s0, ps0, ps1);
    body(2 * tt + 2, true, true, w2rB, w2rA, w1s0, w1s1, ps1, ps0);
  }
  body(31, true, true, w2rA, w2rB, w1s1, w1s0, ps0, ps1);
  body(32, true, false, w2rB, w2rA, w1s0, w1s1, ps1, ps0);   // PV(31) only

  // ---- epilogue: f32, full-line stores ----
  const int crow0 = bm * 128 + wm * 64;
#pragma unroll
  for (int n = 0; n < 4; ++n) {
    const int col = wn * 64 + n * 16 + l15;
    const float bv = b2[col];
#pragma unroll
    for (int m = 0; m < 4; ++m) {
      const int rbase = crow0 + m * 16 + kq * 4;
#pragma unroll
      for (int j = 0; j < 4; ++j) {
        const int row = rbase + j;
        if (row < MROWS) out[(size_t)row * 256 + col] = acc[m][n][j] + bv;
      }
    }
  }
}

// ---------------- MS-deform sampler v2 ----------------
__global__ __launch_bounds__(256)
void sampler_kernel(const float* __restrict__ offattn,   // [M][384]
                    const float* __restrict__ refp,      // [M][4][2]
                    const u16*  __restrict__ value,      // [M][256] bf16
                    u16*        __restrict__ src2)       // [M][256] bf16
{
  __shared__ float2 sWI[2][8][65];

  const int t   = threadIdx.x;
  const int r2  = t >> 7;
  const int g   = t & 127;
  const int row = blockIdx.x * 2 + r2;
  const int b   = row / LQN;

  {
    const int h   = g >> 4;
    const int p16 = g & 15;
    const int l   = p16 >> 2;

    const float* oa = offattn + (size_t)row * 384;

    float logit = oa[256 + h * 16 + p16];
    float mx = logit;
#pragma unroll
    for (int o = 1; o < 16; o <<= 1) mx = fmaxf(mx, __shfl_xor(mx, o, 64));
    float e = __expf(logit - mx);
    float s = e;
#pragma unroll
    for (int o = 1; o < 16; o <<= 1) s += __shfl_xor(s, o, 64);
    const float aw = e / s;

    const int Wl = (l == 0) ? 100 : (l == 1) ? 50 : (l == 2) ? 25 : 13;
    const int Hl = Wl;
    const int st = (l == 0) ? 0 : (l == 1) ? 10000 : (l == 2) ? 12500 : 13125;

    const float ox = oa[(h * 16 + p16) * 2 + 0];
    const float oy = oa[(h * 16 + p16) * 2 + 1];
    const float rx = refp[(size_t)row * 8 + l * 2 + 0] * (float)Wl - 0.5f;
    const float ry = refp[(size_t)row * 8 + l * 2 + 1] * (float)Hl - 0.5f;
    const float gx = rx + ox;
    const float gy = ry + oy;
    const float x0f = floorf(gx), y0f = floorf(gy);
    const int   x0 = (int)x0f, y0 = (int)y0f;
    const float fx = gx - x0f, fy = gy - y0f;

#pragma unroll
    for (int c = 0; c < 4; ++c) {
      const int dx = c & 1, dy = c >> 1;
      const int xi = x0 + dx, yi = y0 + dy;
      const float wx = dx ? fx : 1.0f - fx;
      const float wy = dy ? fy : 1.0f - fy;
      const bool valid = (xi >= 0) && (xi < Wl) && (yi >= 0) && (yi < Hl);
      const int xc = min(max(xi, 0), Wl - 1);
      const int yc = min(max(yi, 0), Hl - 1);
      const int idx = st + yc * Wl + xc;
      const float w = wx * wy * aw * (valid ? 1.0f : 0.0f);
      sWI[r2][h][p16 * 4 + c] = make_float2(w, __builtin_bit_cast(float, idx));
    }
  }
  __syncthreads();

  {
    const int h  = g >> 4;
    const int c2 = g & 15;
    const char* vbase = (const char*)value + (size_t)b * LQN * 512 + h * 64 + c2 * 4;
    const float2* wi = sWI[r2][h];

    float acc0 = 0.f, acc1 = 0.f;
#pragma unroll 16
    for (int e = 0; e < 64; ++e) {
      const float2 p = wi[e];
      const float w  = p.x;
      const int  idx = __builtin_bit_cast(int, p.y);
      const unsigned u = *(const unsigned*)(vbase + (size_t)idx * 512);
      const float f0 = __builtin_bit_cast(float, u << 16);
      const float f1 = __builtin_bit_cast(float, u & 0xffff0000u);
      acc0 += f0 * w;
      acc1 += f1 * w;
    }
    const unsigned o = (unsigned)f2bf(acc0) | ((unsigned)f2bf(acc1) << 16);
    *(unsigned*)&src2[(size_t)row * 256 + h * 32 + c2 * 2] = o;
  }
}

// ---------------- LayerNorm(Xa + Xb): wave per row ----------------
template<int WRITE_BF>
__global__ __launch_bounds__(256)
void ln_kernel(const float* __restrict__ Xa, const float* __restrict__ Xb,
               const float* __restrict__ gam, const float* __restrict__ bet,
               float* __restrict__ Yf, u16* __restrict__ Ybf)
{
  const int wid = threadIdx.x >> 6, lane = threadIdx.x & 63;
  const int row = blockIdx.x * 4 + wid;
  const f32x4 va = ((const f32x4*)(Xa + (size_t)row * 256))[lane];
  const f32x4 vb = ((const f32x4*)(Xb + (size_t)row * 256))[lane];
  f32x4 v = va + vb;
  float s1 = v[0] + v[1] + v[2] + v[3];
  float s2 = v[0] * v[0] + v[1] * v[1] + v[2] * v[2] + v[3] * v[3];
#pragma unroll
  for (int off = 32; off; off >>= 1) {
    s1 += __shfl_xor(s1, off, 64);
    s2 += __shfl_xor(s2, off, 64);
  }
  const float mean = s1 * (1.0f / 256.0f);
  const float var  = s2 * (1.0f / 256.0f) - mean * mean;
  const float rstd = rsqrtf(var + 1e-5f);
  const f32x4 gv = ((const f32x4*)gam)[lane];
  const f32x4 bv = ((const f32x4*)bet)[lane];
  f32x4 y;
#pragma unroll
  for (int j = 0; j < 4; ++j) y[j] = (v[j] - mean) * rstd * gv[j] + bv[j];
  ((f32x4*)(Yf + (size_t)row * 256))[lane] = y;
  if constexpr (WRITE_BF) {
    u16x4 o;
#pragma unroll
    for (int j = 0; j < 4; ++j) o[j] = f2bf(y[j]);
    ((u16x4*)(Ybf + (size_t)row * 256))[lane] = o;
  }
}

// ---------------- prep ----------------
__global__ __launch_bounds__(256)
void prep_qsrc(const float* __restrict__ src, const float* __restrict__ pos,
               u16* __restrict__ src_bf, u16* __restrict__ q_bf)
{
  const size_t i = (size_t)blockIdx.x * 256 + threadIdx.x;
  const f32x4 s = ((const f32x4*)src)[i];
  const f32x4 p = ((const f32x4*)pos)[i];
  u16x4 sb, qb;
#pragma unroll
  for (int j = 0; j < 4; ++j) { sb[j] = f2bf(s[j]); qb[j] = f2bf(s[j] + p[j]); }
  ((u16x4*)src_bf)[i] = sb;
  ((u16x4*)q_bf)[i]   = qb;
}

__global__ __launch_bounds__(256)
void transpose_cast(const float* __restrict__ W, u16* __restrict__ WT, int K, int N)
{
  const int i = blockIdx.x * 256 + threadIdx.x;
  if (i >= K * N) return;
  const int k = i / N, n = i - k * N;
  WT[(size_t)n * K + k] = f2bf(W[i]);
}

__global__ __launch_bounds__(256)
void concat_bias(const float* __restrict__ b_off, const float* __restrict__ b_attn,
                 float* __restrict__ out)
{
  const int i = blockIdx.x * 256 + threadIdx.x;
  if (i < 256) out[i] = b_off[i];
  else if (i < 384) out[i] = b_attn[i - 256];
}

// ---------------- launch ----------------
extern "C" void kernel_launch(void* const* d_in, const int* in_sizes, int n_in,
                              void* d_out, int out_size, void* d_ws, size_t ws_size,
                              hipStream_t stream)
{
  const float* src     = (const float*)d_in[0];
  const float* pos     = (const float*)d_in[1];
  const float* refp    = (const float*)d_in[2];
  const float* w_value = (const float*)d_in[3];
  const float* b_value = (const float*)d_in[4];
  const float* w_off   = (const float*)d_in[5];
  const float* b_off   = (const float*)d_in[6];
  const float* w_attn  = (const float*)d_in[7];
  const float* b_attn  = (const float*)d_in[8];
  const float* w_out   = (const float*)d_in[9];
  const float* b_out   = (const float*)d_in[10];
  const float* ln1_g   = (const float*)d_in[11];
  const float* ln1_b   = (const float*)d_in[12];
  const float* w_ffn1  = (const float*)d_in[13];
  const float* b_ffn1  = (const float*)d_in[14];
  const float* w_ffn2  = (const float*)d_in[15];
  const float* b_ffn2  = (const float*)d_in[16];
  const float* ln2_g   = (const float*)d_in[17];
  const float* ln2_b   = (const float*)d_in[18];

  char* ws = (char*)d_ws;
  size_t off = 0;
  auto alloc = [&](size_t bytes) { void* p = ws + off; off += (bytes + 255) & ~(size_t)255; return p; };

  u16*   src_bf   = (u16*)  alloc((size_t)MROWS * 256 * 2);
  u16*   q_bf     = (u16*)  alloc((size_t)MROWS * 256 * 2);   // later: x_bf
  float* offattn  = (float*)alloc((size_t)MROWS * 384 * 4);   // later: src2p
  u16*   value_bf = (u16*)  alloc((size_t)MROWS * 256 * 2);   // later: ff (f32, spans src2_bf too)
  u16*   src2_bf  = (u16*)  alloc((size_t)MROWS * 256 * 2);
  float* x_f32    = (float*)alloc((size_t)MROWS * 256 * 4);
  u16*   WT_val   = (u16*)  alloc(256 * 256 * 2);
  u16*   WT_oa    = (u16*)  alloc(384 * 256 * 2);
  u16*   WT_out   = (u16*)  alloc(256 * 256 * 2);
  u16*   WT_f1    = (u16*)  alloc(2048 * 256 * 2);
  u16*   WT_f2    = (u16*)  alloc((size_t)256 * 2048 * 2);
  float* bias_oa  = (float*)alloc(384 * 4);

  float* src2p = offattn;            // alias (offattn dead after sampler)
  u16*   x_bf  = q_bf;               // alias (q_bf dead after offattn gemm)
  float* ff    = (float*)value_bf;   // alias (value/src2 dead after out-proj gemm)

  transpose_cast<<<256, 256, 0, stream>>>(w_value, WT_val, 256, 256);
  transpose_cast<<<256, 256, 0, stream>>>(w_off, WT_oa, 256, 256);
  transpose_cast<<<128, 256, 0, stream>>>(w_attn, WT_oa + 256 * 256, 256, 128);
  transpose_cast<<<256, 256, 0, stream>>>(w_out, WT_out, 256, 256);
  transpose_cast<<<2048, 256, 0, stream>>>(w_ffn1, WT_f1, 256, 2048);
  transpose_cast<<<2048, 256, 0, stream>>>(w_ffn2, WT_f2, 2048, 256);
  concat_bias<<<2, 256, 0, stream>>>(b_off, b_attn, bias_oa);

  prep_qsrc<<<6647, 256, 0, stream>>>(src, pos, src_bf, q_bf);

  static bool attr_set = false;
  if (!attr_set) {
    hipFuncSetAttribute((const void*)ffn_fused,
                        hipFuncAttributeMaxDynamicSharedMemorySize, 110592);
    hipFuncSetAttribute((const void*)gemm_k256<0>,
                        hipFuncAttributeMaxDynamicSharedMemorySize, 131072);
    hipFuncSetAttribute((const void*)gemm_k256<1>,
                        hipFuncAttributeMaxDynamicSharedMemorySize, 131072);
    attr_set = true;
  }

  gemm_k256<1><<<dim3(208, 2), 256, 131072, stream>>>(src_bf, WT_val, b_value, value_bf, MROWS, 256);
  gemm_k256<0><<<dim3(208, 3), 256, 131072, stream>>>(q_bf, WT_oa, bias_oa, offattn, MROWS, 384);

  sampler_kernel<<<MROWS / 2, 256, 0, stream>>>(offattn, refp, value_bf, src2_bf);

  gemm_k256<0><<<dim3(208, 2), 256, 131072, stream>>>(src2_bf, WT_out, b_out, src2p, MROWS, 256);

  ln_kernel<1><<<6647, 256, 0, stream>>>(src, src2p, ln1_g, ln1_b, x_f32, x_bf);

  // fused FFN: ff = relu(x@W1+b1)@W2 + b2
  ffn_fused<<<208, 512, 108544, stream>>>(x_bf, WT_f1, WT_f2, b_ffn1, b_ffn2, ff);

  ln_kernel<0><<<6647, 256, 0, stream>>>(x_f32, ff, ln2_g, ln2_b, (float*)d_out, nullptr);
}

// Round 7
// 246.431 us; speedup vs baseline: 1.5686x; 1.5686x over previous
//
#include <hip/hip_runtime.h>

// ---------------- static problem config ----------------
#define LQN   13294
#define NBAT  2
#define MROWS (NBAT * LQN)   // 26588
#define CCH   256
#define NHEAD 8
#define DHEAD 32
#define NLVL  4
#define NPT   4
#define DFF   2048

typedef short short8 __attribute__((ext_vector_type(8)));
typedef float f32x4 __attribute__((ext_vector_type(4)));
typedef unsigned short u16;
typedef u16 u16x4 __attribute__((ext_vector_type(4)));

__device__ __forceinline__ u16 f2bf(float f) {
  unsigned int u = __builtin_bit_cast(unsigned int, f);
  u += 0x7fffu + ((u >> 16) & 1u);   // RNE
  return (u16)(u >> 16);
}
__device__ __forceinline__ float bf2f(u16 s) {
  unsigned int u = ((unsigned int)s) << 16;
  return __builtin_bit_cast(float, u);
}
__device__ __forceinline__ void async16(const void* g, void* l) {
  __builtin_amdgcn_global_load_lds(
      (const __attribute__((address_space(1))) void*)g,
      (__attribute__((address_space(3))) void*)l, 16, 0, 0);
}

// ---------------- bf16 MFMA GEMM (r3): 2-phase dbuf, swizzled ----------------
// OUT_MODE: 0 = f32 out, 1 = bf16 out
template<int OUT_MODE>
__global__ __launch_bounds__(256, 2)
void gemm_bf16(const u16* __restrict__ A, const u16* __restrict__ BT,
               const float* __restrict__ bias, void* __restrict__ Cout,
               int M, int N, int K)
{
  __shared__ u16 As[2][128 * 64];
  __shared__ u16 Bs[2][128 * 64];
  const int t    = threadIdx.x;
  const int lane = t & 63;
  const int wid  = t >> 6;
  const int wm   = wid >> 1, wn = wid & 1;
  const int bm   = blockIdx.x, bn = blockIdx.y;
  const int l15  = lane & 15;
  const int kq   = lane >> 4;

  f32x4 acc[4][4];
#pragma unroll
  for (int m = 0; m < 4; ++m)
#pragma unroll
    for (int n = 0; n < 4; ++n) acc[m][n] = (f32x4)0.0f;

  auto stage = [&](int buf, int kt) {
#pragma unroll
    for (int i = 0; i < 4; ++i) {
      const int c   = i * 256 + t;
      const int row = c >> 3;
      const int kg  = (c & 7) ^ (row & 7);
      int ar = bm * 128 + row; ar = ar < M ? ar : M - 1;
      async16(&A[(size_t)ar * K + kt + kg * 8], &As[buf][c * 8]);
      const int br = bn * 128 + row;
      async16(&BT[(size_t)br * K + kt + kg * 8], &Bs[buf][c * 8]);
    }
  };

  stage(0, 0);
  __syncthreads();
  int cur = 0;

  for (int kt = 0; kt < K; kt += 64) {
    if (kt + 64 < K) stage(cur ^ 1, kt + 64);

#pragma unroll
    for (int kk = 0; kk < 2; ++kk) {
      short8 af[4], bfr[4];
#pragma unroll
      for (int m = 0; m < 4; ++m) {
        const int row = wm * 64 + m * 16 + l15;
        const int xb  = (kk * 64 + kq * 16) ^ ((row & 7) << 4);
        af[m] = *(const short8*)((const char*)&As[cur][0] + row * 128 + xb);
      }
#pragma unroll
      for (int n = 0; n < 4; ++n) {
        const int col = wn * 64 + n * 16 + l15;
        const int xb  = (kk * 64 + kq * 16) ^ ((col & 7) << 4);
        bfr[n] = *(const short8*)((const char*)&Bs[cur][0] + col * 128 + xb);
      }
#pragma unroll
      for (int m = 0; m < 4; ++m)
#pragma unroll
        for (int n = 0; n < 4; ++n)
          acc[m][n] = __builtin_amdgcn_mfma_f32_16x16x32_bf16(af[m], bfr[n], acc[m][n], 0, 0, 0);
    }

    __syncthreads();
    cur ^= 1;
  }

  const int crow0 = bm * 128 + wm * 64;
  const int ccol0 = bn * 128 + wn * 64;
#pragma unroll
  for (int n = 0; n < 4; ++n) {
    int col = ccol0 + n * 16 + l15;
    float bv = bias[col];
#pragma unroll
    for (int m = 0; m < 4; ++m) {
      int rbase = crow0 + m * 16 + kq * 4;
#pragma unroll
      for (int j = 0; j < 4; ++j) {
        int row = rbase + j;
        if (row < M) {
          float v = acc[m][n][j] + bv;
          if constexpr (OUT_MODE == 0) ((float*)Cout)[(size_t)row * N + col] = v;
          else                         ((u16*)Cout)[(size_t)row * N + col] = f2bf(v);
        }
      }
    }
  }
}

// ---------------- dual GEMM: value-proj (bn<2, bf16 out) + off/attn-proj (bn>=2, f32) ----------------
__global__ __launch_bounds__(256, 2)
void gemm_dual(const u16* __restrict__ A0, const u16* __restrict__ BT0,
               const float* __restrict__ bias0, u16* __restrict__ C0,
               const u16* __restrict__ A1, const u16* __restrict__ BT1,
               const float* __restrict__ bias1, float* __restrict__ C1)
{
  __shared__ u16 As[2][128 * 64];
  __shared__ u16 Bs[2][128 * 64];
  const int t    = threadIdx.x;
  const int lane = t & 63;
  const int wid  = t >> 6;
  const int wm   = wid >> 1, wn = wid & 1;
  const int bm   = blockIdx.x;
  const int bnG  = blockIdx.y;
  const bool first = bnG < 2;
  const u16* A    = first ? A0 : A1;
  const u16* BT   = first ? BT0 : BT1;
  const float* bias = first ? bias0 : bias1;
  const int  N    = first ? 256 : 384;
  const int  bn   = first ? bnG : bnG - 2;
  const int l15  = lane & 15;
  const int kq   = lane >> 4;

  f32x4 acc[4][4];
#pragma unroll
  for (int m = 0; m < 4; ++m)
#pragma unroll
    for (int n = 0; n < 4; ++n) acc[m][n] = (f32x4)0.0f;

  auto stage = [&](int buf, int kt) {
#pragma unroll
    for (int i = 0; i < 4; ++i) {
      const int c   = i * 256 + t;
      const int row = c >> 3;
      const int kg  = (c & 7) ^ (row & 7);
      int ar = bm * 128 + row; ar = ar < MROWS ? ar : MROWS - 1;
      async16(&A[(size_t)ar * 256 + kt + kg * 8], &As[buf][c * 8]);
      const int br = bn * 128 + row;
      async16(&BT[(size_t)br * 256 + kt + kg * 8], &Bs[buf][c * 8]);
    }
  };

  stage(0, 0);
  __syncthreads();
  int cur = 0;

  for (int kt = 0; kt < 256; kt += 64) {
    if (kt + 64 < 256) stage(cur ^ 1, kt + 64);

#pragma unroll
    for (int kk = 0; kk < 2; ++kk) {
      short8 af[4], bfr[4];
#pragma unroll
      for (int m = 0; m < 4; ++m) {
        const int row = wm * 64 + m * 16 + l15;
        const int xb  = (kk * 64 + kq * 16) ^ ((row & 7) << 4);
        af[m] = *(const short8*)((const char*)&As[cur][0] + row * 128 + xb);
      }
#pragma unroll
      for (int n = 0; n < 4; ++n) {
        const int col = wn * 64 + n * 16 + l15;
        const int xb  = (kk * 64 + kq * 16) ^ ((col & 7) << 4);
        bfr[n] = *(const short8*)((const char*)&Bs[cur][0] + col * 128 + xb);
      }
#pragma unroll
      for (int m = 0; m < 4; ++m)
#pragma unroll
        for (int n = 0; n < 4; ++n)
          acc[m][n] = __builtin_amdgcn_mfma_f32_16x16x32_bf16(af[m], bfr[n], acc[m][n], 0, 0, 0);
    }

    __syncthreads();
    cur ^= 1;
  }

  const int crow0 = bm * 128 + wm * 64;
  const int ccol0 = bn * 128 + wn * 64;
#pragma unroll
  for (int n = 0; n < 4; ++n) {
    int col = ccol0 + n * 16 + l15;
    float bv = bias[col];
#pragma unroll
    for (int m = 0; m < 4; ++m) {
      int rbase = crow0 + m * 16 + kq * 4;
#pragma unroll
      for (int j = 0; j < 4; ++j) {
        int row = rbase + j;
        if (row < MROWS) {
          float v = acc[m][n][j] + bv;
          if (first) C0[(size_t)row * 256 + col] = f2bf(v);
          else       C1[(size_t)row * 384 + col] = v;
        }
      }
    }
  }
}

// ---------------- fused FFN (r5): x in regs, W1/W2 LDS dbuf, ps conflict-reduced ----------------
__global__ __launch_bounds__(512, 2)
void ffn_fused(const u16* __restrict__ x_bf, const u16* __restrict__ W1T,
               const u16* __restrict__ W2T, const float* __restrict__ b1,
               const float* __restrict__ b2, float* __restrict__ out)
{
  extern __shared__ char smem[];
  u16* w1s = (u16*)(smem);            // [2][64][256]
  u16* w2s = (u16*)(smem + 65536);    // [2][256][64]
  char* ps = (char*)(smem + 131072);  // [128][80] bf16 (160B row stride)

  const int t    = threadIdx.x;
  const int lane = t & 63;
  const int wid  = t >> 6;
  const int l15  = lane & 15;
  const int kq   = lane >> 4;
  const int bm   = blockIdx.x;
  const int pwm  = wid >> 1, pwn = wid & 1;   // P-phase: 4x2, tile 32x32
  const int wm   = wid >> 2, wn = wid & 3;    // PV-phase: 2x4, tile 64x64

  // ---- prologue: x fragments -> registers (once) ----
  short8 xr[2][8];
#pragma unroll
  for (int m = 0; m < 2; ++m) {
    int ar = bm * 128 + pwm * 32 + m * 16 + l15;
    ar = ar < MROWS ? ar : MROWS - 1;
    const char* xb = (const char*)x_bf + (size_t)ar * 512 + kq * 16;
#pragma unroll
    for (int ks = 0; ks < 8; ++ks)
      xr[m][ks] = *(const short8*)(xb + ks * 64);
  }

  auto stage = [&](int buf, int it) {
#pragma unroll
    for (int i = 0; i < 4; ++i) {
      const int c  = i * 512 + t;
      const int r1 = c >> 5;
      const int k1 = ((c & 31) ^ (r1 & 7)) * 8;
      async16(&W1T[(size_t)(it * 64 + r1) * 256 + k1], &w1s[buf * 16384 + c * 8]);
      const int r2 = c >> 3;
      const int k2 = ((c & 7) ^ (r2 & 7)) * 8;
      async16(&W2T[(size_t)r2 * 2048 + it * 64 + k2], &w2s[buf * 16384 + c * 8]);
    }
  };

  f32x4 acc[4][4];
#pragma unroll
  for (int m = 0; m < 4; ++m)
#pragma unroll
    for (int n = 0; n < 4; ++n) acc[m][n] = (f32x4)0.0f;

  stage(0, 0);
  __syncthreads();

  for (int it = 0; it < 32; ++it) {
    const int cur = it & 1;
    if (it < 31) stage(cur ^ 1, it + 1);   // prefetch; drained at mid-iter barrier

    // ---- P = x @ W1c^T (wave tile 32x32), x from registers ----
    f32x4 p[2][2];
#pragma unroll
    for (int m = 0; m < 2; ++m)
#pragma unroll
      for (int n = 0; n < 2; ++n) p[m][n] = (f32x4)0.0f;

#pragma unroll
    for (int ks = 0; ks < 8; ++ks) {
      short8 bfr[2];
#pragma unroll
      for (int n = 0; n < 2; ++n) {
        const int wrow = pwn * 32 + n * 16 + l15;
        const int xb   = (ks * 64 + kq * 16) ^ ((wrow & 7) << 4);
        bfr[n] = *(const short8*)((const char*)&w1s[cur * 16384] + wrow * 512 + xb);
      }
#pragma unroll
      for (int m = 0; m < 2; ++m)
#pragma unroll
        for (int n = 0; n < 2; ++n)
          p[m][n] = __builtin_amdgcn_mfma_f32_16x16x32_bf16(xr[m][ks], bfr[n], p[m][n], 0, 0, 0);
    }

    // ---- bias + relu + bf16 -> ps ----
#pragma unroll
    for (int n = 0; n < 2; ++n) {
      const int col = pwn * 32 + n * 16 + l15;
      const float bv = b1[it * 64 + col];
      const int chnk = col >> 3;
      const int sub  = (col & 7) * 2;
#pragma unroll
      for (int m = 0; m < 2; ++m)
#pragma unroll
        for (int j = 0; j < 4; ++j) {
          const int prow = pwm * 32 + m * 16 + kq * 4 + j;
          const float v = fmaxf(p[m][n][j] + bv, 0.0f);
          *(u16*)(ps + prow * 160 + ((chnk ^ ((prow >> 2) & 3)) << 4) + sub) = f2bf(v);
        }
    }
    __syncthreads();   // ps visible; prefetch drained

    // ---- acc += P @ W2c (wave tile 64x64) ----
#pragma unroll
    for (int kk = 0; kk < 2; ++kk) {
      short8 paf[4], bfr[4];
#pragma unroll
      for (int m = 0; m < 4; ++m) {
        const int arow = wm * 64 + m * 16 + l15;
        const int c    = kk * 4 + kq;
        paf[m] = *(const short8*)(ps + arow * 160 + ((c ^ ((arow >> 2) & 3)) << 4));
      }
#pragma unroll
      for (int n = 0; n < 4; ++n) {
        const int brow = wn * 64 + n * 16 + l15;
        const int xb   = ((kk * 4 + kq) ^ (brow & 7)) * 16;
        bfr[n] = *(const short8*)((const char*)&w2s[cur * 16384] + brow * 128 + xb);
      }
#pragma unroll
      for (int m = 0; m < 4; ++m)
#pragma unroll
        for (int n = 0; n < 4; ++n)
          acc[m][n] = __builtin_amdgcn_mfma_f32_16x16x32_bf16(paf[m], bfr[n], acc[m][n], 0, 0, 0);
    }
    __syncthreads();
  }

  // ---- epilogue: f32, full-line stores ----
  const int crow0 = bm * 128 + wm * 64;
#pragma unroll
  for (int n = 0; n < 4; ++n) {
    const int col = wn * 64 + n * 16 + l15;
    const float bv = b2[col];
#pragma unroll
    for (int m = 0; m < 4; ++m) {
      const int rbase = crow0 + m * 16 + kq * 4;
#pragma unroll
      for (int j = 0; j < 4; ++j) {
        const int row = rbase + j;
        if (row < MROWS) out[(size_t)row * 256 + col] = acc[m][n][j] + bv;
      }
    }
  }
}

// ---------------- MS-deform sampler v3: one wave per row ----------------
// Block = 256 threads = 4 rows. Stage 1: lane computes 2 (head,point) slots
// (softmax via 16-lane shuffle), writes 8 (w,idx) entries to LDS. Stage 2:
// lane owns (head, 4 channels); 64 x 8B gathers, broadcast LDS reads.
__global__ __launch_bounds__(256)
void sampler_kernel(const float* __restrict__ offattn,   // [M][384]
                    const float* __restrict__ refp,      // [M][4][2]
                    const u16*  __restrict__ value,      // [M][256] bf16
                    u16*        __restrict__ src2)       // [M][256] bf16
{
  __shared__ float2 sWI[4][8][65];

  const int t    = threadIdx.x;
  const int r4   = t >> 6;
  const int lane = t & 63;
  const int row  = blockIdx.x * 4 + r4;     // grid exact: 6647*4 = 26588
  const int b    = row / LQN;

  // ---- stage 1 ----
  {
    const float* oa = offattn + (size_t)row * 384;
    const float* rp = refp + (size_t)row * 8;
    const int p16 = lane & 15;
    const int l   = p16 >> 2;
    const int Wl  = (l == 0) ? 100 : (l == 1) ? 50 : (l == 2) ? 25 : 13;
    const int st  = (l == 0) ? 0 : (l == 1) ? 10000 : (l == 2) ? 12500 : 13125;
    const float rx = rp[l * 2 + 0] * (float)Wl - 0.5f;
    const float ry = rp[l * 2 + 1] * (float)Wl - 0.5f;

#pragma unroll
    for (int s = 0; s < 2; ++s) {
      const int h = s * 4 + (lane >> 4);
      float logit = oa[256 + h * 16 + p16];
      float mx = logit;
#pragma unroll
      for (int o = 1; o < 16; o <<= 1) mx = fmaxf(mx, __shfl_xor(mx, o, 64));
      float e = __expf(logit - mx);
      float ssum = e;
#pragma unroll
      for (int o = 1; o < 16; o <<= 1) ssum += __shfl_xor(ssum, o, 64);
      const float aw = e / ssum;

      const float ox = oa[(h * 16 + p16) * 2 + 0];
      const float oy = oa[(h * 16 + p16) * 2 + 1];
      const float gx = rx + ox;
      const float gy = ry + oy;
      const float x0f = floorf(gx), y0f = floorf(gy);
      const int   x0 = (int)x0f, y0 = (int)y0f;
      const float fx = gx - x0f, fy = gy - y0f;
#pragma unroll
      for (int c = 0; c < 4; ++c) {
        const int dx = c & 1, dy = c >> 1;
        const int xi = x0 + dx, yi = y0 + dy;
        const float wx = dx ? fx : 1.0f - fx;
        const float wy = dy ? fy : 1.0f - fy;
        const bool valid = (xi >= 0) && (xi < Wl) && (yi >= 0) && (yi < Wl);
        const int xc = min(max(xi, 0), Wl - 1);
        const int yc = min(max(yi, 0), Wl - 1);
        const int idx = st + yc * Wl + xc;
        const float w = wx * wy * aw * (valid ? 1.0f : 0.0f);
        sWI[r4][h][p16 * 4 + c] = make_float2(w, __builtin_bit_cast(float, idx));
      }
    }
  }
  __syncthreads();

  // ---- stage 2: 8B gathers, 4 channels per lane ----
  {
    const int h  = lane >> 3;
    const int c4 = lane & 7;
    const char* vbase = (const char*)value + (size_t)b * LQN * 512 + h * 64 + c4 * 8;
    const float2* wi = sWI[r4][h];

    float a0 = 0.f, a1 = 0.f, a2 = 0.f, a3 = 0.f;
#pragma unroll 16
    for (int e = 0; e < 64; ++e) {
      const float2 p = wi[e];            // broadcast within 8-lane group
      const float w  = p.x;
      const int  idx = __builtin_bit_cast(int, p.y);
      const unsigned long long u = *(const unsigned long long*)(vbase + (size_t)idx * 512);
      a0 += w * bf2f((u16)(u));
      a1 += w * bf2f((u16)(u >> 16));
      a2 += w * bf2f((u16)(u >> 32));
      a3 += w * bf2f((u16)(u >> 48));
    }
    u16x4 o;
    o[0] = f2bf(a0); o[1] = f2bf(a1); o[2] = f2bf(a2); o[3] = f2bf(a3);
    *(u16x4*)&src2[(size_t)row * 256 + h * 32 + c4 * 4] = o;
  }
}

// ---------------- LayerNorm(Xa + Xb): wave per row ----------------
template<int WRITE_BF>
__global__ __launch_bounds__(256)
void ln_kernel(const float* __restrict__ Xa, const float* __restrict__ Xb,
               const float* __restrict__ gam, const float* __restrict__ bet,
               float* __restrict__ Yf, u16* __restrict__ Ybf)
{
  const int wid = threadIdx.x >> 6, lane = threadIdx.x & 63;
  const int row = blockIdx.x * 4 + wid;
  const f32x4 va = ((const f32x4*)(Xa + (size_t)row * 256))[lane];
  const f32x4 vb = ((const f32x4*)(Xb + (size_t)row * 256))[lane];
  f32x4 v = va + vb;
  float s1 = v[0] + v[1] + v[2] + v[3];
  float s2 = v[0] * v[0] + v[1] * v[1] + v[2] * v[2] + v[3] * v[3];
#pragma unroll
  for (int off = 32; off; off >>= 1) {
    s1 += __shfl_xor(s1, off, 64);
    s2 += __shfl_xor(s2, off, 64);
  }
  const float mean = s1 * (1.0f / 256.0f);
  const float var  = s2 * (1.0f / 256.0f) - mean * mean;
  const float rstd = rsqrtf(var + 1e-5f);
  const f32x4 gv = ((const f32x4*)gam)[lane];
  const f32x4 bv = ((const f32x4*)bet)[lane];
  f32x4 y;
#pragma unroll
  for (int j = 0; j < 4; ++j) y[j] = (v[j] - mean) * rstd * gv[j] + bv[j];
  ((f32x4*)(Yf + (size_t)row * 256))[lane] = y;
  if constexpr (WRITE_BF) {
    u16x4 o;
#pragma unroll
    for (int j = 0; j < 4; ++j) o[j] = f2bf(y[j]);
    ((u16x4*)(Ybf + (size_t)row * 256))[lane] = o;
  }
}

// ---------------- prep ----------------
__global__ __launch_bounds__(256)
void prep_qsrc(const float* __restrict__ src, const float* __restrict__ pos,
               u16* __restrict__ src_bf, u16* __restrict__ q_bf)
{
  const size_t i = (size_t)blockIdx.x * 256 + threadIdx.x;
  const f32x4 s = ((const f32x4*)src)[i];
  const f32x4 p = ((const f32x4*)pos)[i];
  u16x4 sb, qb;
#pragma unroll
  for (int j = 0; j < 4; ++j) { sb[j] = f2bf(s[j]); qb[j] = f2bf(s[j] + p[j]); }
  ((u16x4*)src_bf)[i] = sb;
  ((u16x4*)q_bf)[i]   = qb;
}

// ---------------- fused weight prep: all transposes + bias concat ----------------
// seg sizes: Wv 65536 | Woff 65536 | Wattn 32768 | Wout 65536 | Wf1 524288 | Wf2 524288 | bias 384
__global__ __launch_bounds__(256)
void prep_weights(const float* __restrict__ w_value, const float* __restrict__ w_off,
                  const float* __restrict__ w_attn,  const float* __restrict__ w_out,
                  const float* __restrict__ w_ffn1,  const float* __restrict__ w_ffn2,
                  const float* __restrict__ b_off,   const float* __restrict__ b_attn,
                  u16* __restrict__ WT_val, u16* __restrict__ WT_oa, u16* __restrict__ WT_out,
                  u16* __restrict__ WT_f1,  u16* __restrict__ WT_f2, float* __restrict__ bias_oa)
{
  int i = blockIdx.x * 256 + threadIdx.x;
  if (i < 65536) {                       // w_value [256][256] -> WT_val[n][k]
    const int k = i >> 8, n = i & 255;
    WT_val[n * 256 + k] = f2bf(w_value[i]);
  } else if ((i -= 65536) < 65536) {     // w_off [256][256] -> WT_oa rows 0..255
    const int k = i >> 8, n = i & 255;
    WT_oa[n * 256 + k] = f2bf(w_off[i]);
  } else if ((i -= 65536) < 32768) {     // w_attn [256][128] -> WT_oa rows 256..383
    const int k = i >> 7, n = i & 127;
    WT_oa[(256 + n) * 256 + k] = f2bf(w_attn[i]);
  } else if ((i -= 32768) < 65536) {     // w_out [256][256]
    const int k = i >> 8, n = i & 255;
    WT_out[n * 256 + k] = f2bf(w_out[i]);
  } else if ((i -= 65536) < 524288) {    // w_ffn1 [256][2048]
    const int k = i >> 11, n = i & 2047;
    WT_f1[n * 256 + k] = f2bf(w_ffn1[i]);
  } else if ((i -= 524288) < 524288) {   // w_ffn2 [2048][256]
    const int k = i >> 8, n = i & 255;
    WT_f2[n * 2048 + k] = f2bf(w_ffn2[i]);
  } else if ((i -= 524288) < 384) {      // bias concat
    bias_oa[i] = (i < 256) ? b_off[i] : b_attn[i - 256];
  }
}

// ---------------- launch ----------------
extern "C" void kernel_launch(void* const* d_in, const int* in_sizes, int n_in,
                              void* d_out, int out_size, void* d_ws, size_t ws_size,
                              hipStream_t stream)
{
  const float* src     = (const float*)d_in[0];
  const float* pos     = (const float*)d_in[1];
  const float* refp    = (const float*)d_in[2];
  const float* w_value = (const float*)d_in[3];
  const float* b_value = (const float*)d_in[4];
  const float* w_off   = (const float*)d_in[5];
  const float* b_off   = (const float*)d_in[6];
  const float* w_attn  = (const float*)d_in[7];
  const float* b_attn  = (const float*)d_in[8];
  const float* w_out   = (const float*)d_in[9];
  const float* b_out   = (const float*)d_in[10];
  const float* ln1_g   = (const float*)d_in[11];
  const float* ln1_b   = (const float*)d_in[12];
  const float* w_ffn1  = (const float*)d_in[13];
  const float* b_ffn1  = (const float*)d_in[14];
  const float* w_ffn2  = (const float*)d_in[15];
  const float* b_ffn2  = (const float*)d_in[16];
  const float* ln2_g   = (const float*)d_in[17];
  const float* ln2_b   = (const float*)d_in[18];

  char* ws = (char*)d_ws;
  size_t off = 0;
  auto alloc = [&](size_t bytes) { void* p = ws + off; off += (bytes + 255) & ~(size_t)255; return p; };

  u16*   src_bf   = (u16*)  alloc((size_t)MROWS * 256 * 2);
  u16*   q_bf     = (u16*)  alloc((size_t)MROWS * 256 * 2);   // later: x_bf
  float* offattn  = (float*)alloc((size_t)MROWS * 384 * 4);   // later: src2p
  u16*   value_bf = (u16*)  alloc((size_t)MROWS * 256 * 2);   // later: ff (f32, spans src2_bf too)
  u16*   src2_bf  = (u16*)  alloc((size_t)MROWS * 256 * 2);
  float* x_f32    = (float*)alloc((size_t)MROWS * 256 * 4);
  u16*   WT_val   = (u16*)  alloc(256 * 256 * 2);
  u16*   WT_oa    = (u16*)  alloc(384 * 256 * 2);
  u16*   WT_out   = (u16*)  alloc(256 * 256 * 2);
  u16*   WT_f1    = (u16*)  alloc(2048 * 256 * 2);
  u16*   WT_f2    = (u16*)  alloc((size_t)256 * 2048 * 2);
  float* bias_oa  = (float*)alloc(384 * 4);

  float* src2p = offattn;            // alias (offattn dead after sampler)
  u16*   x_bf  = q_bf;               // alias (q_bf dead after offattn gemm)
  float* ff    = (float*)value_bf;   // alias (value/src2 dead after out-proj gemm)

  prep_weights<<<4994, 256, 0, stream>>>(w_value, w_off, w_attn, w_out, w_ffn1, w_ffn2,
                                         b_off, b_attn,
                                         WT_val, WT_oa, WT_out, WT_f1, WT_f2, bias_oa);

  prep_qsrc<<<6647, 256, 0, stream>>>(src, pos, src_bf, q_bf);

  static bool attr_set = false;
  if (!attr_set) {
    hipFuncSetAttribute((const void*)ffn_fused,
                        hipFuncAttributeMaxDynamicSharedMemorySize, 151552);
    attr_set = true;
  }

  // value-proj + off/attn-proj in one dispatch
  gemm_dual<<<dim3(208, 5), 256, 0, stream>>>(src_bf, WT_val, b_value, value_bf,
                                              q_bf, WT_oa, bias_oa, offattn);

  sampler_kernel<<<MROWS / 4, 256, 0, stream>>>(offattn, refp, value_bf, src2_bf);

  gemm_bf16<0><<<dim3(208, 2), 256, 0, stream>>>(src2_bf, WT_out, b_out, src2p, MROWS, 256, 256);

  ln_kernel<1><<<6647, 256, 0, stream>>>(src, src2p, ln1_g, ln1_b, x_f32, x_bf);

  // fused FFN: ff = relu(x@W1+b1)@W2 + b2
  ffn_fused<<<208, 512, 151552, stream>>>(x_bf, WT_f1, WT_f2, b_ffn1, b_ffn2, ff);

  ln_kernel<0><<<6647, 256, 0, stream>>>(x_f32, ff, ln2_g, ln2_b, (float*)d_out, nullptr);
}